// Round 11
// baseline (168.805 us; speedup 1.0000x reference)
//
#include <hip/hip_runtime.h>
#include <hip/hip_bf16.h>
#include <math.h>

#define NNODES 50000
#define FIN 256
#define HH 4
#define CC 32
#define D1 128   // H*C
#define CLS 16
#define NBUCK ((NNODES + 255) >> 8)   // 196 buckets of 256 nodes
#define CHUNK 4096

typedef __attribute__((ext_vector_type(8))) short bfrag8;   // 8 bf16 = 4 VGPRs
typedef __attribute__((ext_vector_type(4))) float facc4;

__device__ __forceinline__ float lrelu(float x){ return x > 0.f ? x : 0.2f*x; }

// fast exp: v_exp_f32 computes 2^x; scores here are bounded so no special cases.
__device__ __forceinline__ float fexp(float x){
#if __has_builtin(__builtin_amdgcn_exp2f)
  return __builtin_amdgcn_exp2f(x * 1.4426950408889634f);
#else
  return exp2f(x * 1.4426950408889634f);
#endif
}

__device__ __forceinline__ unsigned short f2bu(float x){
  __hip_bfloat16 h = __float2bfloat16(x);
  return *reinterpret_cast<unsigned short*>(&h);
}
__device__ __forceinline__ unsigned int pbf(float a, float b){
  return (unsigned int)f2bu(a) | ((unsigned int)f2bu(b) << 16);
}
__device__ __forceinline__ float2 bf2x(unsigned int u){
  float2 r;
  r.x = __uint_as_float(u << 16);
  r.y = __uint_as_float(u & 0xffff0000u);
  return r;
}

// ---------------- W1 prep: Wt[c][k] = bf16(W1[k][c]) ----------------
__global__ void wprep_kernel(const float* __restrict__ W, unsigned short* __restrict__ Wt) {
  int t = blockIdx.x*256 + threadIdx.x;
  if (t >= FIN*D1) return;
  int k = t >> 7, c = t & 127;
  Wt[c*FIN + k] = f2bu(W[t]);
}

// ---------------- GEMM1 via MFMA: h1b = bf16pairs(x @ W1) ----------------
__global__ __launch_bounds__(256) void gemm1_mfma(const float* __restrict__ x,
                                                  const unsigned int* __restrict__ Wt,
                                                  unsigned int* __restrict__ h1b) {
  __shared__ unsigned int Bs[128*256/2];    // 64 KB: Wt swizzled
  __shared__ unsigned int As[64*64/2];      // 8 KB: x tile swizzled
  int tid = threadIdx.x;
  int wv = tid >> 6, lane = tid & 63;
  int r0 = blockIdx.x * 64;

  for (int it = 0; it < 16; it++) {
    int w16 = it*256 + tid;
    int c = w16 >> 5, k8 = w16 & 31;
    uint4 v = ((const uint4*)Wt)[w16];
    int byt = (c*512 + k8*16) ^ ((c&7)<<4);
    *(uint4*)((char*)Bs + byt) = v;
  }

  facc4 acc[8];
  #pragma unroll
  for (int t=0;t<8;t++) acc[t] = (facc4){0.f,0.f,0.f,0.f};

  int arow = tid >> 2, apart = tid & 3;
  int mrow = lane & 15, kb = lane >> 4;

  for (int stage = 0; stage < 4; stage++) {
    int gr = r0 + arow;
    const float* src = x + (size_t)gr*FIN + stage*64 + apart*16;
    float4 f0, f1, f2, f3;
    if (gr < NNODES) {
      f0 = *(const float4*)(src);
      f1 = *(const float4*)(src+4);
      f2 = *(const float4*)(src+8);
      f3 = *(const float4*)(src+12);
    } else {
      f0 = f1 = f2 = f3 = make_float4(0.f,0.f,0.f,0.f);
    }
    uint4 u0, u1;
    u0.x = pbf(f0.x,f0.y); u0.y = pbf(f0.z,f0.w);
    u0.z = pbf(f1.x,f1.y); u0.w = pbf(f1.z,f1.w);
    u1.x = pbf(f2.x,f2.y); u1.y = pbf(f2.z,f2.w);
    u1.z = pbf(f3.x,f3.y); u1.w = pbf(f3.z,f3.w);
    __syncthreads();
    int b0 = (arow*128 + apart*32) ^ ((arow&7)<<4);
    int b1 = (arow*128 + apart*32 + 16) ^ ((arow&7)<<4);
    *(uint4*)((char*)As + b0) = u0;
    *(uint4*)((char*)As + b1) = u1;
    __syncthreads();
    #pragma unroll
    for (int ks = 0; ks < 2; ks++) {
      int row = wv*16 + mrow;
      int abyt = (row*128 + ks*64 + kb*16) ^ ((row&7)<<4);
      bfrag8 afrag = *(bfrag8*)((char*)As + abyt);
      #pragma unroll
      for (int ct = 0; ct < 8; ct++) {
        int c = ct*16 + mrow;
        int bbyt = (c*512 + stage*128 + ks*64 + kb*16) ^ ((c&7)<<4);
        bfrag8 bfrag = *(bfrag8*)((char*)Bs + bbyt);
        acc[ct] = __builtin_amdgcn_mfma_f32_16x16x32_bf16(afrag, bfrag, acc[ct], 0, 0, 0);
      }
    }
  }
  int orow0 = r0 + wv*16 + (lane>>4)*4;
  int ocol = lane & 15;
  #pragma unroll
  for (int r=0; r<4; r++) {
    int gr = orow0 + r;
    if (gr < NNODES) {
      #pragma unroll
      for (int ct=0; ct<4; ct++)
        h1b[(size_t)gr*64 + ct*16 + ocol] = pbf(acc[ct][r], acc[ct+4][r]);
    }
  }
}

// ---------------- per-node alpha for layer 1 (reads bf16 h1b) ----------------
__global__ void alpha1_kernel(const unsigned int* __restrict__ h1b,
                              const float* __restrict__ asrc,
                              const float* __restrict__ adst,
                              float* __restrict__ as1, float* __restrict__ ad1) {
  int t = blockIdx.x * blockDim.x + threadIdx.x;  // i*H + h
  if (t >= NNODES*HH) return;
  int i = t >> 2, h = t & 3;
  const unsigned int* base = h1b + (size_t)i*64 + (h&1)*32;
  const float* ap = asrc + h*CC;
  const float* bp = adst + h*CC;
  bool hi = (h >= 2);
  float s=0.f, d=0.f;
  #pragma unroll
  for (int q8=0; q8<8; q8++){
    uint4 u = *(const uint4*)(base + q8*4);
    float v0 = hi ? bf2x(u.x).y : bf2x(u.x).x;
    float v1 = hi ? bf2x(u.y).y : bf2x(u.y).x;
    float v2 = hi ? bf2x(u.z).y : bf2x(u.z).x;
    float v3 = hi ? bf2x(u.w).y : bf2x(u.w).x;
    int q = q8*4;
    s = fmaf(v0, ap[q+0], s); d = fmaf(v0, bp[q+0], d);
    s = fmaf(v1, ap[q+1], s); d = fmaf(v1, bp[q+1], d);
    s = fmaf(v2, ap[q+2], s); d = fmaf(v2, bp[q+2], d);
    s = fmaf(v3, ap[q+3], s); d = fmaf(v3, bp[q+3], d);
  }
  as1[t] = s; ad1[t] = d;
}

// ================= bucket-binned CSR build (no random 4B scatter) =================
__global__ __launch_bounds__(256) void bucket_count_kernel(const int* __restrict__ dsts,
                                                           int* __restrict__ bcnt, int E) {
  __shared__ int cnt[NBUCK];
  for (int t=threadIdx.x; t<NBUCK; t+=256) cnt[t]=0;
  __syncthreads();
  int base = blockIdx.x*CHUNK, lim = min(base+CHUNK, E);
  for (int e = base+threadIdx.x; e < lim; e += 256)
    atomicAdd(&cnt[dsts[e]>>8], 1);
  __syncthreads();
  for (int t=threadIdx.x; t<NBUCK; t+=256)
    if (cnt[t]) atomicAdd(&bcnt[t], cnt[t]);
}

__global__ __launch_bounds__(256) void bucket_scan_kernel(const int* __restrict__ bcnt,
                                                          int* __restrict__ gstart,
                                                          int* __restrict__ gcur) {
  int t = threadIdx.x;
  int orig = (t < NBUCK) ? bcnt[t] : 0;
  int v = orig;
  int ln = t & 63, wv = t >> 6;
  #pragma unroll
  for (int off=1; off<64; off<<=1){ int u=__shfl_up(v,off,64); if(ln>=off) v+=u; }
  __shared__ int wsum[4], wbase[4];
  if (ln==63) wsum[wv]=v;
  __syncthreads();
  if (t==0){
    int s=0;
    for(int k=0;k<4;k++){ wbase[k]=s; s+=wsum[k]; }
  }
  __syncthreads();
  int incl = wbase[wv]+v;
  if (t < NBUCK){ gstart[t+1]=incl; gcur[t]=incl-orig; }
  if (t==0) gstart[0]=0;
}

__global__ __launch_bounds__(256) void bin_kernel(const int* __restrict__ srcs,
                                                  const int* __restrict__ dsts,
                                                  int* __restrict__ gcur,
                                                  unsigned int* __restrict__ binned, int E) {
  __shared__ int cnt[NBUCK];
  __shared__ int rbase[NBUCK];
  for (int t=threadIdx.x; t<NBUCK; t+=256) cnt[t]=0;
  __syncthreads();
  int base = blockIdx.x*CHUNK, lim = min(base+CHUNK, E);
  for (int e = base+threadIdx.x; e < lim; e += 256)
    atomicAdd(&cnt[dsts[e]>>8], 1);
  __syncthreads();
  for (int t=threadIdx.x; t<NBUCK; t+=256){
    rbase[t] = cnt[t] ? atomicAdd(&gcur[t], cnt[t]) : 0;
    cnt[t] = 0;
  }
  __syncthreads();
  for (int e = base+threadIdx.x; e < lim; e += 256){
    int d = dsts[e], s = srcs[e];
    int b = d >> 8;
    int p = rbase[b] + atomicAdd(&cnt[b], 1);
    binned[p] = ((unsigned int)s << 8) | (unsigned int)(d & 255);
  }
}

__global__ __launch_bounds__(256) void bucketcsr_kernel(const int* __restrict__ gstart,
                                                        const unsigned int* __restrict__ binned,
                                                        int* __restrict__ offs,
                                                        unsigned short* __restrict__ srcsort, int E) {
  int b = blockIdx.x;
  int s0 = gstart[b], s1 = gstart[b+1];
  int t = threadIdx.x;
  __shared__ int cnt[256];
  __shared__ int cur[256];
  cnt[t] = 0;
  __syncthreads();
  for (int j = s0+t; j < s1; j += 256)
    atomicAdd(&cnt[binned[j] & 255], 1);
  __syncthreads();
  int orig = cnt[t], v = orig;
  int ln = t & 63, wv = t >> 6;
  #pragma unroll
  for (int off=1; off<64; off<<=1){ int u=__shfl_up(v,off,64); if(ln>=off) v+=u; }
  __shared__ int wsum[4], wbase[4];
  if (ln==63) wsum[wv]=v;
  __syncthreads();
  if (t==0){
    int s=0;
    for(int k=0;k<4;k++){ wbase[k]=s; s+=wsum[k]; }
  }
  __syncthreads();
  int excl = wbase[wv] + v - orig;
  cur[t] = excl;
  int node = b*256 + t;
  if (node < NNODES) offs[node] = s0 + excl;
  if (node == NNODES-1) offs[NNODES] = E;
  __syncthreads();
  for (int j = s0+t; j < s1; j += 256){
    unsigned int e = binned[j];
    int p = s0 + atomicAdd(&cur[e & 255], 1);
    srcsort[p] = (unsigned short)(e >> 8);
  }
}

// ---------------- layer-1 softmax + aggregation (+bias+ELU) ----------------
// dwordx4 gathers: 16 lanes per edge, 4 edges in flight.
// lane: cq = lane&15 owns pair-words 4cq..4cq+3 (channels 4cq..4cq+3 and +64);
//       g = lane>>4 is the edge subgroup. Head of lo channels = cq>>3, hi = +2.
__global__ __launch_bounds__(256) void agg1_kernel(
    const unsigned int* __restrict__ h1b, const float* __restrict__ as1,
    const float* __restrict__ ad1, const int* __restrict__ offs,
    const unsigned short* __restrict__ srcsort, const float* __restrict__ b1,
    unsigned int* __restrict__ out1p) {
  __shared__ float exs[4][4][64];   // [warp][head][chunk-slot]
  __shared__ int   ss [4][64];
  int warp = threadIdx.x >> 6;
  int lane = threadIdx.x & 63;
  int i = blockIdx.x * 4 + warp;
  if (i >= NNODES) return;
  int start = offs[i], end = offs[i+1];
  float4 adv = *(const float4*)(ad1 + (size_t)i*4);
  float4 asv = *(const float4*)(as1 + (size_t)i*4);
  float ad[4] = {adv.x, adv.y, adv.z, adv.w};
  float wself[4];
  {
    float av[4] = {asv.x, asv.y, asv.z, asv.w};
    #pragma unroll
    for (int h=0;h<4;h++) wself[h] = fexp(lrelu(av[h] + ad[h]));
  }
  int cq = lane & 15, g = lane >> 4;
  int hlo = cq >> 3, hhi = hlo + 2;
  float den[4] = {0.f, 0.f, 0.f, 0.f};
  float accL[4] = {0.f,0.f,0.f,0.f}, accH[4] = {0.f,0.f,0.f,0.f};
  if (g == 0) {   // self-loop contribution, one group only
    uint4 u = *(const uint4*)(h1b + (size_t)i*64 + 4*cq);
    float wl = wself[hlo], wh = wself[hhi];
    float2 p0 = bf2x(u.x), p1 = bf2x(u.y), p2 = bf2x(u.z), p3 = bf2x(u.w);
    accL[0] = wl*p0.x; accH[0] = wh*p0.y;
    accL[1] = wl*p1.x; accH[1] = wh*p1.y;
    accL[2] = wl*p2.x; accH[2] = wh*p2.y;
    accL[3] = wl*p3.x; accH[3] = wh*p3.y;
  }
  for (int c0 = start; c0 < end; c0 += 64) {
    int cnt = min(64, end - c0);
    int j = c0 + lane;
    if (j < end) {   // fill: one edge per lane
      int s = (int)srcsort[j];
      float4 a = *(const float4*)(as1 + (size_t)s*4);
      float e0 = fexp(lrelu(a.x + ad[0]));
      float e1 = fexp(lrelu(a.y + ad[1]));
      float e2 = fexp(lrelu(a.z + ad[2]));
      float e3 = fexp(lrelu(a.w + ad[3]));
      den[0] += e0; den[1] += e1; den[2] += e2; den[3] += e3;
      exs[warp][0][lane] = e0; exs[warp][1][lane] = e1;
      exs[warp][2][lane] = e2; exs[warp][3][lane] = e3;
      ss[warp][lane] = s;
    }
    // quad loop: group g takes edges g, g+4, g+8, ... (dwordx4 per lane)
    #pragma unroll 4
    for (int j2 = g; j2 < cnt; j2 += 4) {
      int s = ss[warp][j2];
      float wl = exs[warp][hlo][j2];
      float wh = exs[warp][hhi][j2];
      uint4 u = *(const uint4*)(h1b + (size_t)s*64 + 4*cq);
      float2 p0 = bf2x(u.x), p1 = bf2x(u.y), p2 = bf2x(u.z), p3 = bf2x(u.w);
      accL[0] = fmaf(wl, p0.x, accL[0]); accH[0] = fmaf(wh, p0.y, accH[0]);
      accL[1] = fmaf(wl, p1.x, accL[1]); accH[1] = fmaf(wh, p1.y, accH[1]);
      accL[2] = fmaf(wl, p2.x, accL[2]); accH[2] = fmaf(wh, p2.y, accH[2]);
      accL[3] = fmaf(wl, p3.x, accL[3]); accH[3] = fmaf(wh, p3.y, accH[3]);
    }
  }
  // reduce accumulators across the 4 edge-subgroups (lanes differing in bits 4-5)
  #pragma unroll
  for (int off=16; off<64; off<<=1) {
    #pragma unroll
    for (int k=0;k<4;k++) {
      accL[k] += __shfl_xor(accL[k], off, 64);
      accH[k] += __shfl_xor(accH[k], off, 64);
    }
  }
  #pragma unroll
  for (int off=1; off<64; off<<=1) {
    #pragma unroll
    for (int h=0;h<4;h++) den[h] += __shfl_xor(den[h], off, 64);
  }
  if (g == 0) {
    float invlo = 1.f / (den[hlo] + wself[hlo] + 1e-16f);
    float invhi = 1.f / (den[hhi] + wself[hhi] + 1e-16f);
    float4 bL = *(const float4*)(b1 + 4*cq);
    float4 bH = *(const float4*)(b1 + 64 + 4*cq);
    float vL[4], vH[4];
    vL[0]=accL[0]*invlo+bL.x; vL[1]=accL[1]*invlo+bL.y;
    vL[2]=accL[2]*invlo+bL.z; vL[3]=accL[3]*invlo+bL.w;
    vH[0]=accH[0]*invhi+bH.x; vH[1]=accH[1]*invhi+bH.y;
    vH[2]=accH[2]*invhi+bH.z; vH[3]=accH[3]*invhi+bH.w;
    #pragma unroll
    for (int k=0;k<4;k++){
      vL[k] = vL[k] > 0.f ? vL[k] : fexp(vL[k]) - 1.f;   // ELU
      vH[k] = vH[k] > 0.f ? vH[k] : fexp(vH[k]) - 1.f;
    }
    uint4 o;
    o.x = pbf(vL[0], vH[0]); o.y = pbf(vL[1], vH[1]);
    o.z = pbf(vL[2], vH[2]); o.w = pbf(vL[3], vH[3]);
    *(uint4*)(out1p + (size_t)i*64 + 4*cq) = o;
  }
}

// ---------------- layer-2 projection + alphas (reads bf16-pair out1) ----------------
__global__ __launch_bounds__(256) void layer2_proj_kernel(
    const unsigned int* __restrict__ out1p, const float* __restrict__ W2,
    const float* __restrict__ asrc2, const float* __restrict__ adst2,
    __hip_bfloat16* __restrict__ h2b, float* __restrict__ as2, float* __restrict__ ad2) {
  __shared__ float w_s[D1*CLS];
  for (int l = threadIdx.x; l < D1*CLS; l += 256) w_s[l] = W2[l];
  __syncthreads();
  int warp = threadIdx.x >> 6, lane = threadIdx.x & 63;
  int i = blockIdx.x*4 + warp;
  if (i >= NNODES) return;
  int c = lane & 15, kq = lane >> 4;
  const unsigned int* xp = out1p + (size_t)i*64 + (kq&1)*32;
  bool hi = kq >= 2;
  int kb = (kq&1)*32 + (hi ? 64 : 0);
  float acc = 0.f;
  #pragma unroll
  for (int q8=0; q8<8; q8++) {
    uint4 u = *(const uint4*)(xp + q8*4);
    float v0 = hi ? bf2x(u.x).y : bf2x(u.x).x;
    float v1 = hi ? bf2x(u.y).y : bf2x(u.y).x;
    float v2 = hi ? bf2x(u.z).y : bf2x(u.z).x;
    float v3 = hi ? bf2x(u.w).y : bf2x(u.w).x;
    int k = kb + q8*4;
    acc = fmaf(v0, w_s[(k+0)*CLS + c], acc);
    acc = fmaf(v1, w_s[(k+1)*CLS + c], acc);
    acc = fmaf(v2, w_s[(k+2)*CLS + c], acc);
    acc = fmaf(v3, w_s[(k+3)*CLS + c], acc);
  }
  acc += __shfl_xor(acc, 16, 64);
  acc += __shfl_xor(acc, 32, 64);
  if (lane < 16) h2b[(size_t)i*CLS + c] = __float2bfloat16(acc);
  float s = acc * asrc2[c];
  float d = acc * adst2[c];
  #pragma unroll
  for (int off=1; off<16; off<<=1) { s += __shfl_xor(s, off, 64); d += __shfl_xor(d, off, 64); }
  if (lane == 0) { as2[i] = s; ad2[i] = d; }
}

// ---------------- layer-2 softmax + aggregation, two-phase quad gathers ----------------
// fill: 64 lanes compute w per edge into LDS; quad loop: 4 lanes per edge (dwordx2),
// 16 edges in flight. lane: c2 = lane&3 owns words 2c2,2c2+1 (channels 4c2..4c2+3).
__global__ __launch_bounds__(256) void agg2_kernel(
    const unsigned int* __restrict__ h2b, const float* __restrict__ as2,
    const float* __restrict__ ad2, const int* __restrict__ offs,
    const unsigned short* __restrict__ srcsort, const float* __restrict__ b2,
    float* __restrict__ out) {
  __shared__ float wls[4][64];
  __shared__ int   ss2[4][64];
  int warp = threadIdx.x >> 6, lane = threadIdx.x & 63;
  int i = blockIdx.x*4 + warp;
  if (i >= NNODES) return;
  int start = offs[i], end = offs[i+1];
  float ad = ad2[i];
  float wself = fexp(lrelu(as2[i] + ad));
  int c2 = lane & 3, g = lane >> 2;   // 16 edge subgroups
  float acc[4] = {0.f,0.f,0.f,0.f};
  float denp = 0.f;
  if (g == 0) {
    uint2 u = *(const uint2*)(h2b + (size_t)i*8 + 2*c2);
    float2 p0 = bf2x(u.x), p1 = bf2x(u.y);
    acc[0] = wself*p0.x; acc[1] = wself*p0.y;
    acc[2] = wself*p1.x; acc[3] = wself*p1.y;
  }
  if (lane == 0) denp = wself;
  for (int c0 = start; c0 < end; c0 += 64) {
    int cnt = min(64, end - c0);
    int j = c0 + lane;
    if (j < end) {
      int s = (int)srcsort[j];
      float w = fexp(lrelu(as2[s] + ad));
      denp += w;
      wls[warp][lane] = w;
      ss2[warp][lane] = s;
    }
    #pragma unroll 4
    for (int j2 = g; j2 < cnt; j2 += 16) {
      int s = ss2[warp][j2];
      float w = wls[warp][j2];
      uint2 u = *(const uint2*)(h2b + (size_t)s*8 + 2*c2);
      float2 p0 = bf2x(u.x), p1 = bf2x(u.y);
      acc[0] = fmaf(w, p0.x, acc[0]); acc[1] = fmaf(w, p0.y, acc[1]);
      acc[2] = fmaf(w, p1.x, acc[2]); acc[3] = fmaf(w, p1.y, acc[3]);
    }
  }
  #pragma unroll
  for (int off=4; off<64; off<<=1) {
    #pragma unroll
    for (int k=0;k<4;k++) acc[k] += __shfl_xor(acc[k], off, 64);
  }
  #pragma unroll
  for (int off=1; off<64; off<<=1) denp += __shfl_xor(denp, off, 64);
  if (g == 0) {
    float inv = 1.f / (denp + 1e-16f);
    float4 o;
    o.x = acc[0]*inv + b2[4*c2+0];
    o.y = acc[1]*inv + b2[4*c2+1];
    o.z = acc[2]*inv + b2[4*c2+2];
    o.w = acc[3]*inv + b2[4*c2+3];
    *(float4*)(out + (size_t)i*CLS + 4*c2) = o;
  }
}

extern "C" void kernel_launch(void* const* d_in, const int* in_sizes, int n_in,
                              void* d_out, int out_size, void* d_ws, size_t ws_size,
                              hipStream_t stream) {
  const float* x     = (const float*)d_in[0];
  const int*   eidx  = (const int*)d_in[1];
  const float* W1    = (const float*)d_in[2];
  const float* asrc1 = (const float*)d_in[3];
  const float* adst1 = (const float*)d_in[4];
  const float* b1    = (const float*)d_in[5];
  const float* W2    = (const float*)d_in[6];
  const float* asrc2 = (const float*)d_in[7];
  const float* adst2 = (const float*)d_in[8];
  const float* b2    = (const float*)d_in[9];
  float* out = (float*)d_out;

  const int E = in_sizes[1] / 2;
  const int* srcs = eidx;
  const int* dsts = eidx + E;
  const int EBLK = (E + CHUNK - 1) / CHUNK;

  char* ws = (char*)d_ws;
  size_t off = 0;
  auto alloc = [&](size_t bytes) -> void* {
    void* p = ws + off;
    off = (off + bytes + 255) & ~(size_t)255;
    return p;
  };
  unsigned int*   h1b     = (unsigned int*)alloc((size_t)NNODES*(D1/2)*4);
  unsigned int*   out1p   = (unsigned int*)alloc((size_t)NNODES*(D1/2)*4);
  unsigned short* Wt      = (unsigned short*)alloc((size_t)FIN*D1*2);
  float*          as1     = (float*)alloc((size_t)NNODES*HH*4);
  float*          ad1     = (float*)alloc((size_t)NNODES*HH*4);
  __hip_bfloat16* h2b     = (__hip_bfloat16*)alloc((size_t)NNODES*CLS*2);
  float*          as2     = (float*)alloc((size_t)NNODES*4);
  float*          ad2     = (float*)alloc((size_t)NNODES*4);
  int*            bcnt    = (int*)alloc((size_t)NBUCK*4);
  int*            gstart  = (int*)alloc((size_t)(NBUCK+1)*4);
  int*            gcur    = (int*)alloc((size_t)NBUCK*4);
  int*            offs    = (int*)alloc((size_t)(NNODES+1)*4);
  unsigned int*   binned  = (unsigned int*)alloc((size_t)E*4);
  unsigned short* srcsort = (unsigned short*)alloc((size_t)E*2);

  (void)hipMemsetAsync(bcnt, 0, (size_t)NBUCK*4, stream);

  // layer 1 projection via MFMA (writes bf16 pairs only)
  wprep_kernel<<<(FIN*D1+255)/256, 256, 0, stream>>>(W1, Wt);
  gemm1_mfma<<<(NNODES+63)/64, 256, 0, stream>>>(x, (const unsigned int*)Wt, h1b);
  alpha1_kernel<<<(NNODES*HH+255)/256, 256, 0, stream>>>(h1b, asrc1, adst1, as1, ad1);

  // bucket-binned CSR build
  bucket_count_kernel<<<EBLK, 256, 0, stream>>>(dsts, bcnt, E);
  bucket_scan_kernel<<<1, 256, 0, stream>>>(bcnt, gstart, gcur);
  bin_kernel<<<EBLK, 256, 0, stream>>>(srcs, dsts, gcur, binned, E);
  bucketcsr_kernel<<<NBUCK, 256, 0, stream>>>(gstart, binned, offs, srcsort, E);

  // layer 1 attention + aggregation (+bias+ELU)
  agg1_kernel<<<(NNODES+3)/4, 256, 0, stream>>>(h1b, as1, ad1, offs, srcsort, b1, out1p);

  // layer 2
  layer2_proj_kernel<<<(NNODES+3)/4, 256, 0, stream>>>(out1p, W2, asrc2, adst2, h2b, as2, ad2);
  agg2_kernel<<<(NNODES+3)/4, 256, 0, stream>>>((const unsigned int*)h2b, as2, ad2, offs, srcsort, b2, out);
}

// Round 12
// 153.033 us; speedup vs baseline: 1.1031x; 1.1031x over previous
//
#include <hip/hip_runtime.h>
#include <hip/hip_bf16.h>
#include <math.h>

#define NNODES 50000
#define FIN 256
#define HH 4
#define CC 32
#define D1 128   // H*C
#define CLS 16
#define NBUCK ((NNODES + 255) >> 8)   // 196 buckets of 256 nodes
#define CHUNK 4096

typedef __attribute__((ext_vector_type(8))) short bfrag8;   // 8 bf16 = 4 VGPRs
typedef __attribute__((ext_vector_type(4))) float facc4;

__device__ __forceinline__ float lrelu(float x){ return x > 0.f ? x : 0.2f*x; }

// fast exp: v_exp_f32 computes 2^x; scores here are bounded so no special cases.
__device__ __forceinline__ float fexp(float x){
#if __has_builtin(__builtin_amdgcn_exp2f)
  return __builtin_amdgcn_exp2f(x * 1.4426950408889634f);
#else
  return exp2f(x * 1.4426950408889634f);
#endif
}

__device__ __forceinline__ unsigned short f2bu(float x){
  __hip_bfloat16 h = __float2bfloat16(x);
  return *reinterpret_cast<unsigned short*>(&h);
}
__device__ __forceinline__ unsigned int pbf(float a, float b){
  return (unsigned int)f2bu(a) | ((unsigned int)f2bu(b) << 16);
}
__device__ __forceinline__ float2 bf2x(unsigned int u){
  float2 r;
  r.x = __uint_as_float(u << 16);
  r.y = __uint_as_float(u & 0xffff0000u);
  return r;
}

// ---------------- W1 prep: Wt[c][k] = bf16(W1[k][c]) ----------------
__global__ void wprep_kernel(const float* __restrict__ W, unsigned short* __restrict__ Wt) {
  int t = blockIdx.x*256 + threadIdx.x;
  if (t >= FIN*D1) return;
  int k = t >> 7, c = t & 127;
  Wt[c*FIN + k] = f2bu(W[t]);
}

// ---------------- GEMM1 via MFMA: h1b = bf16pairs(x @ W1), fused alpha ----------------
// block: 64 rows x 128 cols x K=256. 4 waves; wave w owns rows w*16..w*16+15.
// Epilogue also computes as1/ad1 (per-head dots with asrc/adst) via 16-lane butterfly —
// this replaced the standalone alpha1 kernel (round 12).
__global__ __launch_bounds__(256) void gemm1_mfma(const float* __restrict__ x,
                                                  const unsigned int* __restrict__ Wt,
                                                  const float* __restrict__ asrc,
                                                  const float* __restrict__ adst,
                                                  unsigned int* __restrict__ h1b,
                                                  float* __restrict__ as1,
                                                  float* __restrict__ ad1) {
  __shared__ unsigned int Bs[128*256/2];    // 64 KB: Wt swizzled
  __shared__ unsigned int As[64*64/2];      // 8 KB: x tile swizzled
  int tid = threadIdx.x;
  int wv = tid >> 6, lane = tid & 63;
  int r0 = blockIdx.x * 64;

  for (int it = 0; it < 16; it++) {
    int w16 = it*256 + tid;
    int c = w16 >> 5, k8 = w16 & 31;
    uint4 v = ((const uint4*)Wt)[w16];
    int byt = (c*512 + k8*16) ^ ((c&7)<<4);
    *(uint4*)((char*)Bs + byt) = v;
  }

  facc4 acc[8];
  #pragma unroll
  for (int t=0;t<8;t++) acc[t] = (facc4){0.f,0.f,0.f,0.f};

  int arow = tid >> 2, apart = tid & 3;
  int mrow = lane & 15, kb = lane >> 4;

  for (int stage = 0; stage < 4; stage++) {
    int gr = r0 + arow;
    const float* src = x + (size_t)gr*FIN + stage*64 + apart*16;
    float4 f0, f1, f2, f3;
    if (gr < NNODES) {
      f0 = *(const float4*)(src);
      f1 = *(const float4*)(src+4);
      f2 = *(const float4*)(src+8);
      f3 = *(const float4*)(src+12);
    } else {
      f0 = f1 = f2 = f3 = make_float4(0.f,0.f,0.f,0.f);
    }
    uint4 u0, u1;
    u0.x = pbf(f0.x,f0.y); u0.y = pbf(f0.z,f0.w);
    u0.z = pbf(f1.x,f1.y); u0.w = pbf(f1.z,f1.w);
    u1.x = pbf(f2.x,f2.y); u1.y = pbf(f2.z,f2.w);
    u1.z = pbf(f3.x,f3.y); u1.w = pbf(f3.z,f3.w);
    __syncthreads();
    int b0 = (arow*128 + apart*32) ^ ((arow&7)<<4);
    int b1 = (arow*128 + apart*32 + 16) ^ ((arow&7)<<4);
    *(uint4*)((char*)As + b0) = u0;
    *(uint4*)((char*)As + b1) = u1;
    __syncthreads();
    #pragma unroll
    for (int ks = 0; ks < 2; ks++) {
      int row = wv*16 + mrow;
      int abyt = (row*128 + ks*64 + kb*16) ^ ((row&7)<<4);
      bfrag8 afrag = *(bfrag8*)((char*)As + abyt);
      #pragma unroll
      for (int ct = 0; ct < 8; ct++) {
        int c = ct*16 + mrow;
        int bbyt = (c*512 + stage*128 + ks*64 + kb*16) ^ ((c&7)<<4);
        bfrag8 bfrag = *(bfrag8*)((char*)Bs + bbyt);
        acc[ct] = __builtin_amdgcn_mfma_f32_16x16x32_bf16(afrag, bfrag, acc[ct], 0, 0, 0);
      }
    }
  }
  // epilogue: D layout col=lane&15, row=(lane>>4)*4+reg.
  int orow0 = r0 + wv*16 + (lane>>4)*4;
  int ocol = lane & 15;
  // lane's 8 channels are ct*16+ocol; head of ct is ct>>1.
  float asr[8], adr[8];
  #pragma unroll
  for (int ct=0; ct<8; ct++){
    asr[ct] = asrc[ct*16 + ocol];
    adr[ct] = adst[ct*16 + ocol];
  }
  #pragma unroll
  for (int r=0; r<4; r++) {
    int gr = orow0 + r;
    float sh[4], dh[4];
    #pragma unroll
    for (int h=0; h<4; h++){
      sh[h] = acc[2*h][r]*asr[2*h] + acc[2*h+1][r]*asr[2*h+1];
      dh[h] = acc[2*h][r]*adr[2*h] + acc[2*h+1][r]*adr[2*h+1];
    }
    #pragma unroll
    for (int off=1; off<16; off<<=1){
      #pragma unroll
      for (int h=0;h<4;h++){
        sh[h] += __shfl_xor(sh[h], off, 64);
        dh[h] += __shfl_xor(dh[h], off, 64);
      }
    }
    if (gr < NNODES) {
      if (ocol == 0) {
        *(float4*)(as1 + (size_t)gr*4) = make_float4(sh[0], sh[1], sh[2], sh[3]);
        *(float4*)(ad1 + (size_t)gr*4) = make_float4(dh[0], dh[1], dh[2], dh[3]);
      }
      #pragma unroll
      for (int ct=0; ct<4; ct++)
        h1b[(size_t)gr*64 + ct*16 + ocol] = pbf(acc[ct][r], acc[ct+4][r]);
    }
  }
}

// ================= bucket-binned CSR build (no random 4B scatter) =================
__global__ __launch_bounds__(256) void bucket_count_kernel(const int* __restrict__ dsts,
                                                           int* __restrict__ bcnt, int E) {
  __shared__ int cnt[NBUCK];
  for (int t=threadIdx.x; t<NBUCK; t+=256) cnt[t]=0;
  __syncthreads();
  int base = blockIdx.x*CHUNK, lim = min(base+CHUNK, E);
  for (int e = base+threadIdx.x; e < lim; e += 256)
    atomicAdd(&cnt[dsts[e]>>8], 1);
  __syncthreads();
  for (int t=threadIdx.x; t<NBUCK; t+=256)
    if (cnt[t]) atomicAdd(&bcnt[t], cnt[t]);
}

__global__ __launch_bounds__(256) void bucket_scan_kernel(const int* __restrict__ bcnt,
                                                          int* __restrict__ gstart,
                                                          int* __restrict__ gcur) {
  int t = threadIdx.x;
  int orig = (t < NBUCK) ? bcnt[t] : 0;
  int v = orig;
  int ln = t & 63, wv = t >> 6;
  #pragma unroll
  for (int off=1; off<64; off<<=1){ int u=__shfl_up(v,off,64); if(ln>=off) v+=u; }
  __shared__ int wsum[4], wbase[4];
  if (ln==63) wsum[wv]=v;
  __syncthreads();
  if (t==0){
    int s=0;
    for(int k=0;k<4;k++){ wbase[k]=s; s+=wsum[k]; }
  }
  __syncthreads();
  int incl = wbase[wv]+v;
  if (t < NBUCK){ gstart[t+1]=incl; gcur[t]=incl-orig; }
  if (t==0) gstart[0]=0;
}

__global__ __launch_bounds__(256) void bin_kernel(const int* __restrict__ srcs,
                                                  const int* __restrict__ dsts,
                                                  int* __restrict__ gcur,
                                                  unsigned int* __restrict__ binned, int E) {
  __shared__ int cnt[NBUCK];
  __shared__ int rbase[NBUCK];
  for (int t=threadIdx.x; t<NBUCK; t+=256) cnt[t]=0;
  __syncthreads();
  int base = blockIdx.x*CHUNK, lim = min(base+CHUNK, E);
  for (int e = base+threadIdx.x; e < lim; e += 256)
    atomicAdd(&cnt[dsts[e]>>8], 1);
  __syncthreads();
  for (int t=threadIdx.x; t<NBUCK; t+=256){
    rbase[t] = cnt[t] ? atomicAdd(&gcur[t], cnt[t]) : 0;
    cnt[t] = 0;
  }
  __syncthreads();
  for (int e = base+threadIdx.x; e < lim; e += 256){
    int d = dsts[e], s = srcs[e];
    int b = d >> 8;
    int p = rbase[b] + atomicAdd(&cnt[b], 1);
    binned[p] = ((unsigned int)s << 8) | (unsigned int)(d & 255);
  }
}

__global__ __launch_bounds__(256) void bucketcsr_kernel(const int* __restrict__ gstart,
                                                        const unsigned int* __restrict__ binned,
                                                        int* __restrict__ offs,
                                                        unsigned short* __restrict__ srcsort, int E) {
  int b = blockIdx.x;
  int s0 = gstart[b], s1 = gstart[b+1];
  int t = threadIdx.x;
  __shared__ int cnt[256];
  __shared__ int cur[256];
  cnt[t] = 0;
  __syncthreads();
  for (int j = s0+t; j < s1; j += 256)
    atomicAdd(&cnt[binned[j] & 255], 1);
  __syncthreads();
  int orig = cnt[t], v = orig;
  int ln = t & 63, wv = t >> 6;
  #pragma unroll
  for (int off=1; off<64; off<<=1){ int u=__shfl_up(v,off,64); if(ln>=off) v+=u; }
  __shared__ int wsum[4], wbase[4];
  if (ln==63) wsum[wv]=v;
  __syncthreads();
  if (t==0){
    int s=0;
    for(int k=0;k<4;k++){ wbase[k]=s; s+=wsum[k]; }
  }
  __syncthreads();
  int excl = wbase[wv] + v - orig;
  cur[t] = excl;
  int node = b*256 + t;
  if (node < NNODES) offs[node] = s0 + excl;
  if (node == NNODES-1) offs[NNODES] = E;
  __syncthreads();
  for (int j = s0+t; j < s1; j += 256){
    unsigned int e = binned[j];
    int p = s0 + atomicAdd(&cur[e & 255], 1);
    srcsort[p] = (unsigned short)(e >> 8);
  }
}

// ---------------- layer-1 softmax + aggregation (+bias+ELU), no-max softmax ----------------
// ROUND-10 VERSION (round-11 quad-gather regressed: VGPR 36->48, occ 56->43%, +bank conflicts).
// out1p pair word p = bf16(channel p, channel p+64)
__global__ __launch_bounds__(256) void agg1_kernel(
    const unsigned int* __restrict__ h1b, const float* __restrict__ as1,
    const float* __restrict__ ad1, const int* __restrict__ offs,
    const unsigned short* __restrict__ srcsort, const float* __restrict__ b1,
    unsigned int* __restrict__ out1p) {
  __shared__ float exs[4][4][64];   // [warp][head][chunk-slot]
  __shared__ int   ss [4][64];
  int warp = threadIdx.x >> 6;
  int lane = threadIdx.x & 63;
  int i = blockIdx.x * 4 + warp;
  if (i >= NNODES) return;
  int start = offs[i], end = offs[i+1];
  float4 adv = *(const float4*)(ad1 + (size_t)i*4);
  float4 asv = *(const float4*)(as1 + (size_t)i*4);
  float ad[4] = {adv.x, adv.y, adv.z, adv.w};
  float wself[4];
  {
    float av[4] = {asv.x, asv.y, asv.z, asv.w};
    #pragma unroll
    for (int h=0;h<4;h++) wself[h] = fexp(lrelu(av[h] + ad[h]));
  }
  int hlo = lane >> 5, hhi = hlo + 2;
  float den[4] = {0.f, 0.f, 0.f, 0.f};
  float accA, accB;
  {
    float2 hv = bf2x(h1b[(size_t)i*64 + lane]);
    accA = wself[hlo] * hv.x; accB = wself[hhi] * hv.y;
  }
  for (int c0 = start; c0 < end; c0 += 64) {
    int cnt = min(64, end - c0);
    int j = c0 + lane;
    if (j < end) {
      int s = (int)srcsort[j];
      float4 a = *(const float4*)(as1 + (size_t)s*4);
      float e0 = fexp(lrelu(a.x + ad[0]));
      float e1 = fexp(lrelu(a.y + ad[1]));
      float e2 = fexp(lrelu(a.z + ad[2]));
      float e3 = fexp(lrelu(a.w + ad[3]));
      den[0] += e0; den[1] += e1; den[2] += e2; den[3] += e3;
      exs[warp][0][lane] = e0; exs[warp][1][lane] = e1;
      exs[warp][2][lane] = e2; exs[warp][3][lane] = e3;
      ss[warp][lane] = s;
    }
    // 8 loads in flight hides the ~500cy L2/L3-miss latency (round-9/10 finding).
    #pragma unroll 8
    for (int j2 = 0; j2 < cnt; j2++) {
      int s = ss[warp][j2];
      float2 hv = bf2x(h1b[(size_t)s*64 + lane]);
      accA = fmaf(exs[warp][hlo][j2], hv.x, accA);
      accB = fmaf(exs[warp][hhi][j2], hv.y, accB);
    }
  }
  #pragma unroll
  for (int off=1; off<64; off<<=1) {
    #pragma unroll
    for (int h=0;h<4;h++) den[h] += __shfl_xor(den[h], off, 64);
  }
  float invlo = 1.f / (den[hlo] + wself[hlo] + 1e-16f);
  float invhi = 1.f / (den[hhi] + wself[hhi] + 1e-16f);
  float v0 = accA * invlo + b1[lane];
  float v1 = accB * invhi + b1[lane + 64];
  v0 = v0 > 0.f ? v0 : fexp(v0) - 1.f;   // ELU
  v1 = v1 > 0.f ? v1 : fexp(v1) - 1.f;
  out1p[(size_t)i*64 + lane] = pbf(v0, v1);
}

// ---------------- layer-2 projection + alphas (reads bf16-pair out1) ----------------
__global__ __launch_bounds__(256) void layer2_proj_kernel(
    const unsigned int* __restrict__ out1p, const float* __restrict__ W2,
    const float* __restrict__ asrc2, const float* __restrict__ adst2,
    __hip_bfloat16* __restrict__ h2b, float* __restrict__ as2, float* __restrict__ ad2) {
  __shared__ float w_s[D1*CLS];
  for (int l = threadIdx.x; l < D1*CLS; l += 256) w_s[l] = W2[l];
  __syncthreads();
  int warp = threadIdx.x >> 6, lane = threadIdx.x & 63;
  int i = blockIdx.x*4 + warp;
  if (i >= NNODES) return;
  int c = lane & 15, kq = lane >> 4;
  const unsigned int* xp = out1p + (size_t)i*64 + (kq&1)*32;
  bool hi = kq >= 2;
  int kb = (kq&1)*32 + (hi ? 64 : 0);
  float acc = 0.f;
  #pragma unroll
  for (int q8=0; q8<8; q8++) {
    uint4 u = *(const uint4*)(xp + q8*4);
    float v0 = hi ? bf2x(u.x).y : bf2x(u.x).x;
    float v1 = hi ? bf2x(u.y).y : bf2x(u.y).x;
    float v2 = hi ? bf2x(u.z).y : bf2x(u.z).x;
    float v3 = hi ? bf2x(u.w).y : bf2x(u.w).x;
    int k = kb + q8*4;
    acc = fmaf(v0, w_s[(k+0)*CLS + c], acc);
    acc = fmaf(v1, w_s[(k+1)*CLS + c], acc);
    acc = fmaf(v2, w_s[(k+2)*CLS + c], acc);
    acc = fmaf(v3, w_s[(k+3)*CLS + c], acc);
  }
  acc += __shfl_xor(acc, 16, 64);
  acc += __shfl_xor(acc, 32, 64);
  if (lane < 16) h2b[(size_t)i*CLS + c] = __float2bfloat16(acc);
  float s = acc * asrc2[c];
  float d = acc * adst2[c];
  #pragma unroll
  for (int off=1; off<16; off<<=1) { s += __shfl_xor(s, off, 64); d += __shfl_xor(d, off, 64); }
  if (lane == 0) { as2[i] = s; ad2[i] = d; }
}

// ---------------- layer-2 softmax + aggregation, single pass (round-10 version) ----------------
__global__ __launch_bounds__(256) void agg2_kernel(
    const unsigned int* __restrict__ h2b, const float* __restrict__ as2,
    const float* __restrict__ ad2, const int* __restrict__ offs,
    const unsigned short* __restrict__ srcsort, const float* __restrict__ b2,
    float* __restrict__ out) {
  int warp = threadIdx.x >> 6, lane = threadIdx.x & 63;
  int i = blockIdx.x*4 + warp;
  if (i >= NNODES) return;
  int start = offs[i], end = offs[i+1];
  float ad = ad2[i];
  float wself = fexp(lrelu(as2[i] + ad));
  int g = lane >> 3, cp = lane & 7;
  float2 acc = make_float2(0.f, 0.f);
  float denp = 0.f;
  if (g == 0) {
    float2 hv = bf2x(h2b[(size_t)i*(CLS/2) + cp]);
    acc.x = wself*hv.x; acc.y = wself*hv.y;
    denp = wself;
  }
  #pragma unroll 4
  for (int j = start + g; j < end; j += 8) {
    int s = (int)srcsort[j];
    float w = fexp(lrelu(as2[s] + ad));
    denp += w;
    float2 hv = bf2x(h2b[(size_t)s*(CLS/2) + cp]);
    acc.x = fmaf(w, hv.x, acc.x);
    acc.y = fmaf(w, hv.y, acc.y);
  }
  #pragma unroll
  for (int off=8; off<64; off<<=1) {
    acc.x += __shfl_xor(acc.x, off, 64);
    acc.y += __shfl_xor(acc.y, off, 64);
    denp  += __shfl_xor(denp,  off, 64);
  }
  if (lane < 8) {
    float inv = 1.f / (denp + 1e-16f);
    float2 o;
    o.x = acc.x * inv + b2[2*cp];
    o.y = acc.y * inv + b2[2*cp+1];
    *(float2*)(out + (size_t)i*CLS + 2*cp) = o;
  }
}

extern "C" void kernel_launch(void* const* d_in, const int* in_sizes, int n_in,
                              void* d_out, int out_size, void* d_ws, size_t ws_size,
                              hipStream_t stream) {
  const float* x     = (const float*)d_in[0];
  const int*   eidx  = (const int*)d_in[1];
  const float* W1    = (const float*)d_in[2];
  const float* asrc1 = (const float*)d_in[3];
  const float* adst1 = (const float*)d_in[4];
  const float* b1    = (const float*)d_in[5];
  const float* W2    = (const float*)d_in[6];
  const float* asrc2 = (const float*)d_in[7];
  const float* adst2 = (const float*)d_in[8];
  const float* b2    = (const float*)d_in[9];
  float* out = (float*)d_out;

  const int E = in_sizes[1] / 2;
  const int* srcs = eidx;
  const int* dsts = eidx + E;
  const int EBLK = (E + CHUNK - 1) / CHUNK;

  char* ws = (char*)d_ws;
  size_t off = 0;
  auto alloc = [&](size_t bytes) -> void* {
    void* p = ws + off;
    off = (off + bytes + 255) & ~(size_t)255;
    return p;
  };
  unsigned int*   h1b     = (unsigned int*)alloc((size_t)NNODES*(D1/2)*4);
  unsigned int*   out1p   = (unsigned int*)alloc((size_t)NNODES*(D1/2)*4);
  unsigned short* Wt      = (unsigned short*)alloc((size_t)FIN*D1*2);
  float*          as1     = (float*)alloc((size_t)NNODES*HH*4);
  float*          ad1     = (float*)alloc((size_t)NNODES*HH*4);
  __hip_bfloat16* h2b     = (__hip_bfloat16*)alloc((size_t)NNODES*CLS*2);
  float*          as2     = (float*)alloc((size_t)NNODES*4);
  float*          ad2     = (float*)alloc((size_t)NNODES*4);
  int*            bcnt    = (int*)alloc((size_t)NBUCK*4);
  int*            gstart  = (int*)alloc((size_t)(NBUCK+1)*4);
  int*            gcur    = (int*)alloc((size_t)NBUCK*4);
  int*            offs    = (int*)alloc((size_t)(NNODES+1)*4);
  unsigned int*   binned  = (unsigned int*)alloc((size_t)E*4);
  unsigned short* srcsort = (unsigned short*)alloc((size_t)E*2);

  (void)hipMemsetAsync(bcnt, 0, (size_t)NBUCK*4, stream);

  // layer 1 projection via MFMA (+fused alpha, writes bf16 pairs only)
  wprep_kernel<<<(FIN*D1+255)/256, 256, 0, stream>>>(W1, Wt);
  gemm1_mfma<<<(NNODES+63)/64, 256, 0, stream>>>(x, (const unsigned int*)Wt,
                                                 asrc1, adst1, h1b, as1, ad1);

  // bucket-binned CSR build
  bucket_count_kernel<<<EBLK, 256, 0, stream>>>(dsts, bcnt, E);
  bucket_scan_kernel<<<1, 256, 0, stream>>>(bcnt, gstart, gcur);
  bin_kernel<<<EBLK, 256, 0, stream>>>(srcs, dsts, gcur, binned, E);
  bucketcsr_kernel<<<NBUCK, 256, 0, stream>>>(gstart, binned, offs, srcsort, E);

  // layer 1 attention + aggregation (+bias+ELU)
  agg1_kernel<<<(NNODES+3)/4, 256, 0, stream>>>(h1b, as1, ad1, offs, srcsort, b1, out1p);

  // layer 2
  layer2_proj_kernel<<<(NNODES+3)/4, 256, 0, stream>>>(out1p, W2, asrc2, adst2, h2b, as2, ad2);
  agg2_kernel<<<(NNODES+3)/4, 256, 0, stream>>>((const unsigned int*)h2b, as2, ad2, offs, srcsort, b2, out);
}